// Round 3
// baseline (561.832 us; speedup 1.0000x reference)
//
#include <hip/hip_runtime.h>
#include <cstdint>
#include <cstddef>

// ---------------------------------------------------------------------------
// DynaResidualBlock: hypernet GEMM (MFMA, hi/lo bf16 split = fp32-accurate)
//  -> per-sample 1x1 conv chain (bf16 MFMA)
//   FIN=64 FOUT=64 FH=128 LAT=512  B=16  H*W=16384
//   sizes = [8192,16384,16384,8192,4096,128,128,128,64,64], KTOT=53760
// ---------------------------------------------------------------------------

typedef short bf16x8 __attribute__((ext_vector_type(8)));   // 8 bf16 = 4 VGPRs
typedef float f32x4  __attribute__((ext_vector_type(4)));
typedef float f32x16 __attribute__((ext_vector_type(16)));  // MFMA 32x32 acc

#define DEVFN static __device__ __forceinline__

constexpr int WELEM      = 53248;           // bf16 weight elements per sample
constexpr size_t WS_WSHORTS = (size_t)WELEM;
constexpr size_t WS_WBYTES_TOT = (size_t)16 * WELEM * 2;     // 1,703,936
constexpr size_t WS_BOFF  = WS_WBYTES_TOT;                   // b_ws: 16*512 f32
constexpr size_t WS_AHOFF = WS_BOFF + 16 * 512 * 4;          // ah frags: 16 KB
constexpr size_t WS_ALOFF = WS_AHOFF + 16384;                // al frags: 16 KB

DEVFN unsigned bf16rne(float f) {
  unsigned u = __builtin_bit_cast(unsigned, f);
  return (u + 0x7fffu + ((u >> 16) & 1u)) >> 16;
}
DEVFN unsigned pk2(float lo, float hi) {
  return bf16rne(lo) | (bf16rne(hi) << 16);
}

// ---------------------------------------------------------------------------
// Kernel 0: lat -> hi/lo bf16 A-frags for mfma_16x16x32.
// frag element (s, lane l, j): A[m=l&15][k = s*32 + (l>>4)*8 + j]
// stored at ah_ws[(s*64+l)*8 + j]. 1024 (s,l) pairs.
// ---------------------------------------------------------------------------
__global__ __launch_bounds__(256) void lat_prep(
    const float* __restrict__ lat, unsigned short* __restrict__ ah_ws,
    unsigned short* __restrict__ al_ws) {
  const int id = blockIdx.x * 256 + threadIdx.x;  // 0..1023
  const int s = id >> 6, l = id & 63;
  const int m = l & 15, q = l >> 4;
  const float* ap = lat + m * 512 + s * 32 + q * 8;
  float f[8];
#pragma unroll
  for (int j = 0; j < 8; ++j) f[j] = ap[j];
  unsigned H[4], L[4];
#pragma unroll
  for (int p = 0; p < 4; ++p) {
    const unsigned u0 = __builtin_bit_cast(unsigned, f[2 * p]);
    const unsigned u1 = __builtin_bit_cast(unsigned, f[2 * p + 1]);
    const unsigned h0 = u0 & 0xFFFF0000u, h1 = u1 & 0xFFFF0000u;
    H[p] = (h0 >> 16) | h1;
    const float lo0 = f[2 * p] - __builtin_bit_cast(float, h0);
    const float lo1 = f[2 * p + 1] - __builtin_bit_cast(float, h1);
    L[p] = pk2(lo0, lo1);
  }
  *(uint4*)&ah_ws[(size_t)(s * 64 + l) * 8] = make_uint4(H[0], H[1], H[2], H[3]);
  *(uint4*)&al_ws[(size_t)(s * 64 + l) * 8] = make_uint4(L[0], L[1], L[2], L[3]);
}

// ---------------------------------------------------------------------------
// Kernel 1: ks = lat @ W.T + bias via MFMA 16x16x32 (hi/lo split, 3 mfma/step)
// One 16-column tile per wave; 3360 tiles = 840 blocks x 4 waves.
// Wave streams its 16 W rows (columns of ks) with an 8-step float4 ring
// (16 KB in flight per wave). Epilogue scatters to frag-layout bf16 ws.
// ---------------------------------------------------------------------------
#define MFMA16(A, B, C) __builtin_amdgcn_mfma_f32_16x16x32_bf16((A), (B), (C), 0, 0, 0)

__global__ __launch_bounds__(256, 2) void hyper_gemm(
    const float* __restrict__ W, const float* __restrict__ bias,
    const unsigned short* __restrict__ ah_ws,
    const unsigned short* __restrict__ al_ws,
    unsigned short* __restrict__ w_ws, float* __restrict__ b_ws) {
  const int tid = threadIdx.x;
  const int wv = tid >> 6;
  const int l = tid & 63;
  const int q = l >> 4;
  const int g = blockIdx.x * 4 + wv;  // tile id 0..3359
  const int n0 = g * 16;
  const int n = n0 + (l & 15);

  // A frags (shared by all waves; L2-hot)
  bf16x8 Ah[16], Al[16];
#pragma unroll
  for (int s = 0; s < 16; ++s) {
    Ah[s] = *(const bf16x8*)&ah_ws[(size_t)(s * 64 + l) * 8];
    Al[s] = *(const bf16x8*)&al_ws[(size_t)(s * 64 + l) * 8];
  }

  // B stream: lane reads W[n][s*32 + q*8 .. +8]
  const float* bp = W + (size_t)n * 512 + q * 8;
  float4 ld[8][2];
#pragma unroll
  for (int s = 0; s < 8; ++s) {
    ld[s][0] = *(const float4*)(bp + s * 32);
    ld[s][1] = *(const float4*)(bp + s * 32 + 4);
  }

  f32x4 acc = {0.f, 0.f, 0.f, 0.f};
#pragma unroll
  for (int s = 0; s < 16; ++s) {
    const float4 b0 = ld[s & 7][0];
    const float4 b1 = ld[s & 7][1];
    if (s < 8) {
      ld[s][0] = *(const float4*)(bp + (s + 8) * 32);
      ld[s][1] = *(const float4*)(bp + (s + 8) * 32 + 4);
    }
    const float f[8] = {b0.x, b0.y, b0.z, b0.w, b1.x, b1.y, b1.z, b1.w};
    union { unsigned u[4]; bf16x8 v; } BH, BL;
#pragma unroll
    for (int p = 0; p < 4; ++p) {
      const unsigned u0 = __builtin_bit_cast(unsigned, f[2 * p]);
      const unsigned u1 = __builtin_bit_cast(unsigned, f[2 * p + 1]);
      const unsigned h0 = u0 & 0xFFFF0000u, h1 = u1 & 0xFFFF0000u;
      BH.u[p] = (h0 >> 16) | h1;
      const float lo0 = f[2 * p] - __builtin_bit_cast(float, h0);
      const float lo1 = f[2 * p + 1] - __builtin_bit_cast(float, h1);
      BL.u[p] = pk2(lo0, lo1);
    }
    acc = MFMA16(Ah[s], BH.v, acc);
    acc = MFMA16(Ah[s], BL.v, acc);
    acc = MFMA16(Al[s], BH.v, acc);
  }

  // epilogue: lane holds column n, samples b = q*4 + r  (D: col=l&15, row=q*4+r)
  const float bv = bias[n];
  if (n0 >= 53248) {  // conv biases: fp32, per-sample contiguous [512]
    const int j = n - 53248;
#pragma unroll
    for (int r = 0; r < 4; ++r) b_ws[(q * 4 + r) * 512 + j] = acc[r] + bv;
    return;
  }
  int fragbase, off, kbits;
  float scale;
  if (n < 8192)       { fragbase = 0;  off = 0;     kbits = 6; scale = 0.08838834764831845f; }
  else if (n < 24576) { fragbase = 16; off = 8192;  kbits = 7; scale = 0.08838834764831845f; }
  else if (n < 40960) { fragbase = 48; off = 24576; kbits = 7; scale = 0.08838834764831845f; }
  else if (n < 49152) { fragbase = 80; off = 40960; kbits = 7; scale = 0.125f; }
  else                { fragbase = 96; off = 49152; kbits = 6; scale = 0.125f; }
  const int r0 = n - off;
  const int m = r0 >> kbits;
  const int k = r0 & ((1 << kbits) - 1);
  const int mt = m >> 5, ks = k >> 4;
  const int lane = (m & 31) + 32 * ((k >> 3) & 1);
  const int j = k & 7;
  const int frag = fragbase + mt * (1 << (kbits - 4)) + ks;
  const size_t eoff = (size_t)frag * 512 + lane * 8 + j;  // in shorts
#pragma unroll
  for (int r = 0; r < 4; ++r) {
    const float v = (acc[r] + bv) * scale;
    w_ws[(size_t)(q * 4 + r) * WS_WSHORTS + eoff] = (unsigned short)bf16rne(v);
  }
}

// ---------------------------------------------------------------------------
// Kernel 2: per-sample conv chain, v4.
// 256 blocks (sample = blk>>4, chunk = blk&15), 8 waves (512 thr), each wave
// owns 32 px/iter (nt=1), 4 iters -> 1024 px/block. In-register h handoff
// (permlane32_swap, proven correct + 0 bank conflicts in v2/v3) now FITS the
// 256 arch-VGPR file: live set = hA 32 + hB2 32 + xf 16 + xr 32 + acc + temps
// ~= 175 regs.  History: v2 (512 thr, LB(512,2)) capped VGPR at 128 -> 900 MB
// scratch spill; v3 (256 thr, nt=2, LB(256,1)) hit the 256 arch ceiling with
// a ~280-reg live set -> 400 MB spill. nt=1 is the fit. 8 waves = 2/SIMD
// (2x every prior version's latency hiding). LDS = 104 weight frags
// (106.5 KB) + bias, 1 block/CU. A-frag ds_read:MFMA ratio drops to 1:1 ->
// LDS floor ~11 us, VALU ~10 us: both << the 76 us v1 baseline.
//   C layout (32x32): col=l&31, row=(reg&3)+8*(reg>>2)+4*(l>>5)
//   B layout (32x32x16): n=l&31, k=8*(l>>5)+j
//   => with P[G][w]=pk2(acc[4G+2w],acc[4G+2w+1]),
//      r = permlane32_swap(P[2e][w], P[2e+1][w]) gives
//      r[0]={a.lo,b.lo} = B word j=(2w,2w+1), r[1]={a.hi,b.hi} = j=(2w+4,2w+5)
//      of frag ks=2*mt+e.
// ---------------------------------------------------------------------------

DEVFN f32x16 bias_init(const float* bl, int mt, int lh) {
  f32x16 a;
#pragma unroll
  for (int g = 0; g < 4; ++g) {
    const float4 bv = *(const float4*)&bl[mt * 32 + 8 * g + 4 * lh];
    a[4 * g + 0] = bv.x; a[4 * g + 1] = bv.y;
    a[4 * g + 2] = bv.z; a[4 * g + 3] = bv.w;
  }
  return a;
}

// acc of output-channel tile mt -> relu -> 2 B-frags h[2*mt+e]
// (frag ks=2*mt+e covers channels 16ks..16ks+15)
DEVFN void acc_to_bfrags1(const f32x16& a0, bf16x8* h, int mt) {
  unsigned P[4][2];  // [G][w]
#pragma unroll
  for (int g = 0; g < 4; ++g) {
    P[g][0] = pk2(fmaxf(a0[4 * g + 0], 0.f), fmaxf(a0[4 * g + 1], 0.f));
    P[g][1] = pk2(fmaxf(a0[4 * g + 2], 0.f), fmaxf(a0[4 * g + 3], 0.f));
  }
#pragma unroll
  for (int e = 0; e < 2; ++e) {
    auto r0 = __builtin_amdgcn_permlane32_swap(P[2 * e][0], P[2 * e + 1][0], false, false);
    auto r1 = __builtin_amdgcn_permlane32_swap(P[2 * e][1], P[2 * e + 1][1], false, false);
    union { unsigned u[4]; bf16x8 v; } F;
    F.u[0] = r0[0]; F.u[1] = r1[0]; F.u[2] = r0[1]; F.u[3] = r1[1];
    h[2 * mt + e] = F.v;
  }
}

#define MFMA32(A, B, C) __builtin_amdgcn_mfma_f32_32x32x16_bf16((A), (B), (C), 0, 0, 0)

__global__ __launch_bounds__(512, 1) void dyn_conv(
    const float* __restrict__ x, const unsigned short* __restrict__ w_ws,
    const float* __restrict__ b_ws, float* __restrict__ out) {
  // LDS frag order = w_ws layout: in[0..16) mida[16..48) midb[48..80)
  //                               out[80..96) short[96..104)
  __shared__ short wl[104 * 512];  // 106496 B
  __shared__ float bl[512];        //   2048 B

  const int s = blockIdx.x >> 4;
  const int chunk = blockIdx.x & 15;
  const int tid = threadIdx.x;
  const int wv = tid >> 6;       // 0..7
  const int l = tid & 63;
  const int l31 = l & 31;
  const int lh = l >> 5;

  const unsigned short* wbase = w_ws + (size_t)s * WS_WSHORTS;
  const float* xbase = x + (size_t)(s * 64) * 16384;

  float xr[4][8];  // 32 floats: this iter's 32 px x 64 ch slice for this lane
  auto load_xr = [&](int it2) {
    const int px0 = chunk * 1024 + it2 * 256 + wv * 32;
#pragma unroll
    for (int ks = 0; ks < 4; ++ks) {
      const float* xp =
          xbase + (size_t)(ks * 16 + lh * 8) * 16384 + px0 + l31;
#pragma unroll
      for (int j = 0; j < 8; ++j) xr[ks][j] = xp[(size_t)j * 16384];
    }
  };
  // iter-0 x loads first: HBM latency overlaps the weight staging below
  load_xr(0);

  // stage ALL weights -> LDS (w_ws frag layout is contiguous; copy verbatim)
  for (int f = wv; f < 104; f += 8)
    *(int4*)&wl[f * 512 + l * 8] = *(const int4*)&wbase[(size_t)f * 512 + l * 8];
  bl[tid] = b_ws[s * 512 + tid];

  __syncthreads();

#pragma unroll 1
  for (int it = 0; it < 4; ++it) {
    const int px0 = chunk * 1024 + it * 256 + wv * 32;

    // pack current x regs -> bf16 B-frags (used by IN and SHORT stages)
    bf16x8 xf[4];
#pragma unroll
    for (int ks = 0; ks < 4; ++ks) {
      union { unsigned u[4]; bf16x8 v8; } uu;
#pragma unroll
      for (int j = 0; j < 4; ++j)
        uu.u[j] = pk2(xr[ks][2 * j], xr[ks][2 * j + 1]);
      xf[ks] = uu.v8;
    }
    // prefetch next iteration's x; latency overlaps all four MFMA stages
    if (it < 3) load_xr(it + 1);

    bf16x8 hA[8], hB2[8];

    // ---- stage IN: h1 = relu(k_in @ x + b_in)   (M=128, K=64) -> hA
#pragma unroll
    for (int mt = 0; mt < 4; ++mt) {
      f32x16 a0 = bias_init(bl + 0, mt, lh);
#pragma unroll
      for (int ks = 0; ks < 4; ++ks) {
        const bf16x8 A = *(const bf16x8*)&wl[(mt * 4 + ks) * 512 + l * 8];
        a0 = MFMA32(A, xf[ks], a0);
      }
      acc_to_bfrags1(a0, hA, mt);
    }

    // ---- stage MIDA: h2 = relu(k_mida @ h1 + b) (M=128, K=128) hA -> hB2
#pragma unroll
    for (int mt = 0; mt < 4; ++mt) {
      f32x16 a0 = bias_init(bl + 128, mt, lh);
#pragma unroll
      for (int ks = 0; ks < 8; ++ks) {
        const bf16x8 A = *(const bf16x8*)&wl[(16 + mt * 8 + ks) * 512 + l * 8];
        a0 = MFMA32(A, hA[ks], a0);
      }
      acc_to_bfrags1(a0, hB2, mt);
    }

    // ---- stage MIDB: h3 = relu(k_midb @ h2 + b) (M=128, K=128) hB2 -> hA
#pragma unroll
    for (int mt = 0; mt < 4; ++mt) {
      f32x16 a0 = bias_init(bl + 256, mt, lh);
#pragma unroll
      for (int ks = 0; ks < 8; ++ks) {
        const bf16x8 A = *(const bf16x8*)&wl[(48 + mt * 8 + ks) * 512 + l * 8];
        a0 = MFMA32(A, hB2[ks], a0);
      }
      acc_to_bfrags1(a0, hA, mt);
    }

    // ---- stage OUT: out = k_out@h3 + k_short@x + b_out + b_short  (M=64)
#pragma unroll
    for (int mt = 0; mt < 2; ++mt) {
      f32x16 a0 = bias_init(bl + 384, mt, lh);
      {
        const f32x16 bs = bias_init(bl + 448, mt, lh);
#pragma unroll
        for (int e = 0; e < 16; ++e) a0[e] += bs[e];
      }
#pragma unroll
      for (int ks = 0; ks < 4; ++ks) {  // shortcut: K=64, B = x frags
        const bf16x8 A = *(const bf16x8*)&wl[(96 + mt * 4 + ks) * 512 + l * 8];
        a0 = MFMA32(A, xf[ks], a0);
      }
#pragma unroll
      for (int ks = 0; ks < 8; ++ks) {  // k_out: K=128, B = h3
        const bf16x8 A = *(const bf16x8*)&wl[(80 + mt * 8 + ks) * 512 + l * 8];
        a0 = MFMA32(A, hA[ks], a0);
      }
#pragma unroll
      for (int g = 0; g < 4; ++g) {
#pragma unroll
        for (int q = 0; q < 4; ++q) {
          const int row = mt * 32 + 8 * g + 4 * lh + q;
          out[(size_t)(s * 64 + row) * 16384 + px0 + l31] = a0[4 * g + q];
        }
      }
    }
  }
}

// ---------------------------------------------------------------------------
extern "C" void kernel_launch(void* const* d_in, const int* in_sizes, int n_in,
                              void* d_out, int out_size, void* d_ws,
                              size_t ws_size, hipStream_t stream) {
  (void)in_sizes; (void)n_in; (void)out_size; (void)ws_size;
  const float* x   = (const float*)d_in[0];
  const float* lat = (const float*)d_in[1];
  const float* W   = (const float*)d_in[2];
  const float* b   = (const float*)d_in[3];
  unsigned short* w_ws = (unsigned short*)d_ws;
  float* b_ws = (float*)((char*)d_ws + WS_BOFF);
  unsigned short* ah_ws = (unsigned short*)((char*)d_ws + WS_AHOFF);
  unsigned short* al_ws = (unsigned short*)((char*)d_ws + WS_ALOFF);
  float* out = (float*)d_out;

  lat_prep<<<dim3(4), dim3(256), 0, stream>>>(lat, ah_ws, al_ws);
  hyper_gemm<<<dim3(840), dim3(256), 0, stream>>>(W, b, ah_ws, al_ws, w_ws, b_ws);
  dyn_conv<<<dim3(256), dim3(512), 0, stream>>>(x, w_ws, b_ws, out);
}

// Round 4
// 428.114 us; speedup vs baseline: 1.3123x; 1.3123x over previous
//
#include <hip/hip_runtime.h>
#include <cstdint>
#include <cstddef>

// ---------------------------------------------------------------------------
// DynaResidualBlock: hypernet GEMM (MFMA, hi/lo bf16 split = fp32-accurate)
//  -> per-sample 1x1 conv chain (bf16 MFMA)
//   FIN=64 FOUT=64 FH=128 LAT=512  B=16  H*W=16384
//   sizes = [8192,16384,16384,8192,4096,128,128,128,64,64], KTOT=53760
// ---------------------------------------------------------------------------

typedef short bf16x8 __attribute__((ext_vector_type(8)));   // 8 bf16 = 4 VGPRs
typedef float f32x4  __attribute__((ext_vector_type(4)));
typedef float f32x16 __attribute__((ext_vector_type(16)));  // MFMA 32x32 acc

#define DEVFN static __device__ __forceinline__

constexpr int WELEM      = 53248;           // bf16 weight elements per sample
constexpr size_t WS_WSHORTS = (size_t)WELEM;
constexpr size_t WS_WBYTES_TOT = (size_t)16 * WELEM * 2;     // 1,703,936
constexpr size_t WS_BOFF  = WS_WBYTES_TOT;                   // b_ws: 16*512 f32
constexpr size_t WS_AHOFF = WS_BOFF + 16 * 512 * 4;          // ah frags: 16 KB
constexpr size_t WS_ALOFF = WS_AHOFF + 16384;                // al frags: 16 KB

DEVFN unsigned bf16rne(float f) {
  unsigned u = __builtin_bit_cast(unsigned, f);
  return (u + 0x7fffu + ((u >> 16) & 1u)) >> 16;
}
DEVFN unsigned pk2(float lo, float hi) {
  return bf16rne(lo) | (bf16rne(hi) << 16);
}

// ---------------------------------------------------------------------------
// Kernel 0: lat -> hi/lo bf16 A-frags for mfma_16x16x32.
// frag element (s, lane l, j): A[m=l&15][k = s*32 + (l>>4)*8 + j]
// stored at ah_ws[(s*64+l)*8 + j]. 1024 (s,l) pairs.
// ---------------------------------------------------------------------------
__global__ __launch_bounds__(256) void lat_prep(
    const float* __restrict__ lat, unsigned short* __restrict__ ah_ws,
    unsigned short* __restrict__ al_ws) {
  const int id = blockIdx.x * 256 + threadIdx.x;  // 0..1023
  const int s = id >> 6, l = id & 63;
  const int m = l & 15, q = l >> 4;
  const float* ap = lat + m * 512 + s * 32 + q * 8;
  float f[8];
#pragma unroll
  for (int j = 0; j < 8; ++j) f[j] = ap[j];
  unsigned H[4], L[4];
#pragma unroll
  for (int p = 0; p < 4; ++p) {
    const unsigned u0 = __builtin_bit_cast(unsigned, f[2 * p]);
    const unsigned u1 = __builtin_bit_cast(unsigned, f[2 * p + 1]);
    const unsigned h0 = u0 & 0xFFFF0000u, h1 = u1 & 0xFFFF0000u;
    H[p] = (h0 >> 16) | h1;
    const float lo0 = f[2 * p] - __builtin_bit_cast(float, h0);
    const float lo1 = f[2 * p + 1] - __builtin_bit_cast(float, h1);
    L[p] = pk2(lo0, lo1);
  }
  *(uint4*)&ah_ws[(size_t)(s * 64 + l) * 8] = make_uint4(H[0], H[1], H[2], H[3]);
  *(uint4*)&al_ws[(size_t)(s * 64 + l) * 8] = make_uint4(L[0], L[1], L[2], L[3]);
}

// ---------------------------------------------------------------------------
// Kernel 1: ks = lat @ W.T + bias via MFMA 16x16x32 (hi/lo split, 3 mfma/step)
// One 16-column tile per wave; 3360 tiles = 840 blocks x 4 waves.
// Wave streams its 16 W rows (columns of ks) with an 8-step float4 ring
// (16 KB in flight per wave). Epilogue scatters to frag-layout bf16 ws.
// ---------------------------------------------------------------------------
#define MFMA16(A, B, C) __builtin_amdgcn_mfma_f32_16x16x32_bf16((A), (B), (C), 0, 0, 0)

__global__ __launch_bounds__(256, 2) void hyper_gemm(
    const float* __restrict__ W, const float* __restrict__ bias,
    const unsigned short* __restrict__ ah_ws,
    const unsigned short* __restrict__ al_ws,
    unsigned short* __restrict__ w_ws, float* __restrict__ b_ws) {
  const int tid = threadIdx.x;
  const int wv = tid >> 6;
  const int l = tid & 63;
  const int q = l >> 4;
  const int g = blockIdx.x * 4 + wv;  // tile id 0..3359
  const int n0 = g * 16;
  const int n = n0 + (l & 15);

  // A frags (shared by all waves; L2-hot)
  bf16x8 Ah[16], Al[16];
#pragma unroll
  for (int s = 0; s < 16; ++s) {
    Ah[s] = *(const bf16x8*)&ah_ws[(size_t)(s * 64 + l) * 8];
    Al[s] = *(const bf16x8*)&al_ws[(size_t)(s * 64 + l) * 8];
  }

  // B stream: lane reads W[n][s*32 + q*8 .. +8]
  const float* bp = W + (size_t)n * 512 + q * 8;
  float4 ld[8][2];
#pragma unroll
  for (int s = 0; s < 8; ++s) {
    ld[s][0] = *(const float4*)(bp + s * 32);
    ld[s][1] = *(const float4*)(bp + s * 32 + 4);
  }

  f32x4 acc = {0.f, 0.f, 0.f, 0.f};
#pragma unroll
  for (int s = 0; s < 16; ++s) {
    const float4 b0 = ld[s & 7][0];
    const float4 b1 = ld[s & 7][1];
    if (s < 8) {
      ld[s][0] = *(const float4*)(bp + (s + 8) * 32);
      ld[s][1] = *(const float4*)(bp + (s + 8) * 32 + 4);
    }
    const float f[8] = {b0.x, b0.y, b0.z, b0.w, b1.x, b1.y, b1.z, b1.w};
    union { unsigned u[4]; bf16x8 v; } BH, BL;
#pragma unroll
    for (int p = 0; p < 4; ++p) {
      const unsigned u0 = __builtin_bit_cast(unsigned, f[2 * p]);
      const unsigned u1 = __builtin_bit_cast(unsigned, f[2 * p + 1]);
      const unsigned h0 = u0 & 0xFFFF0000u, h1 = u1 & 0xFFFF0000u;
      BH.u[p] = (h0 >> 16) | h1;
      const float lo0 = f[2 * p] - __builtin_bit_cast(float, h0);
      const float lo1 = f[2 * p + 1] - __builtin_bit_cast(float, h1);
      BL.u[p] = pk2(lo0, lo1);
    }
    acc = MFMA16(Ah[s], BH.v, acc);
    acc = MFMA16(Ah[s], BL.v, acc);
    acc = MFMA16(Al[s], BH.v, acc);
  }

  // epilogue: lane holds column n, samples b = q*4 + r  (D: col=l&15, row=q*4+r)
  const float bv = bias[n];
  if (n0 >= 53248) {  // conv biases: fp32, per-sample contiguous [512]
    const int j = n - 53248;
#pragma unroll
    for (int r = 0; r < 4; ++r) b_ws[(q * 4 + r) * 512 + j] = acc[r] + bv;
    return;
  }
  int fragbase, off, kbits;
  float scale;
  if (n < 8192)       { fragbase = 0;  off = 0;     kbits = 6; scale = 0.08838834764831845f; }
  else if (n < 24576) { fragbase = 16; off = 8192;  kbits = 7; scale = 0.08838834764831845f; }
  else if (n < 40960) { fragbase = 48; off = 24576; kbits = 7; scale = 0.08838834764831845f; }
  else if (n < 49152) { fragbase = 80; off = 40960; kbits = 7; scale = 0.125f; }
  else                { fragbase = 96; off = 49152; kbits = 6; scale = 0.125f; }
  const int r0 = n - off;
  const int m = r0 >> kbits;
  const int k = r0 & ((1 << kbits) - 1);
  const int mt = m >> 5, ks = k >> 4;
  const int lane = (m & 31) + 32 * ((k >> 3) & 1);
  const int j = k & 7;
  const int frag = fragbase + mt * (1 << (kbits - 4)) + ks;
  const size_t eoff = (size_t)frag * 512 + lane * 8 + j;  // in shorts
#pragma unroll
  for (int r = 0; r < 4; ++r) {
    const float v = (acc[r] + bv) * scale;
    w_ws[(size_t)(q * 4 + r) * WS_WSHORTS + eoff] = (unsigned short)bf16rne(v);
  }
}

// ---------------------------------------------------------------------------
// Kernel 2: per-sample conv chain, v5.
// 256 blocks (sample = blk>>4, chunk = blk&15), 4 waves (256 thr), each wave
// owns 32 px/iter (nt=1), 8 iters -> 1024 px/block.
// REGISTER-BUDGET HISTORY (the controlling constraint):
//   v1: 256thr nt=2 h-in-LDS   -> 236 VGPR, no spill, 76 us (baseline)
//   v2: 512thr nt=2 in-reg h   -> compiler caps at 128 VGPR -> 900 MB spill
//   v3: 256thr nt=2 in-reg h   -> 256 VGPR ceiling < ~280 live -> 400 MB spill
//   v4: 512thr nt=1 in-reg h   -> 512-thr blocks AGAIN capped at 128 -> spill
//   => 512-thread blocks get a hard 128-VGPR cap on this compiler regardless
//      of __launch_bounds__; 256-thread blocks get the full file.
// v5 = the uncovered cell: 256 threads + nt=1 + in-reg permlane h handoff.
// Live set ~170 regs (xr 32 + xf 16 + hA 32 + hB2 32 + acc 16 + temps) < 236.
// Permlane handoff is refcheck-proven (v2/v3/v4 all passed) and measured
// SQ_LDS_BANK_CONFLICT == 0. LDS = 104 weight frags (106.5 KB) + bias.
//   C layout (32x32): col=l&31, row=(reg&3)+8*(reg>>2)+4*(l>>5)
//   B layout (32x32x16): n=l&31, k=8*(l>>5)+j
//   => with P[G][w]=pk2(acc[4G+2w],acc[4G+2w+1]),
//      r = permlane32_swap(P[2e][w], P[2e+1][w]) gives
//      r[0]={a.lo,b.lo} = B word j=(2w,2w+1), r[1]={a.hi,b.hi} = j=(2w+4,2w+5)
//      of frag ks=2*mt+e.
// Next-iter x prefetch issued right after the xf pack; HBM latency hides
// under the four MFMA stages (~1.5K cyc/iter).
// ---------------------------------------------------------------------------

DEVFN f32x16 bias_init(const float* bl, int mt, int lh) {
  f32x16 a;
#pragma unroll
  for (int g = 0; g < 4; ++g) {
    const float4 bv = *(const float4*)&bl[mt * 32 + 8 * g + 4 * lh];
    a[4 * g + 0] = bv.x; a[4 * g + 1] = bv.y;
    a[4 * g + 2] = bv.z; a[4 * g + 3] = bv.w;
  }
  return a;
}

// acc of output-channel tile mt -> relu -> 2 B-frags h[2*mt+e]
// (frag ks=2*mt+e covers channels 16ks..16ks+15)
DEVFN void acc_to_bfrags1(const f32x16& a0, bf16x8* h, int mt) {
  unsigned P[4][2];  // [G][w]
#pragma unroll
  for (int g = 0; g < 4; ++g) {
    P[g][0] = pk2(fmaxf(a0[4 * g + 0], 0.f), fmaxf(a0[4 * g + 1], 0.f));
    P[g][1] = pk2(fmaxf(a0[4 * g + 2], 0.f), fmaxf(a0[4 * g + 3], 0.f));
  }
#pragma unroll
  for (int e = 0; e < 2; ++e) {
    auto r0 = __builtin_amdgcn_permlane32_swap(P[2 * e][0], P[2 * e + 1][0], false, false);
    auto r1 = __builtin_amdgcn_permlane32_swap(P[2 * e][1], P[2 * e + 1][1], false, false);
    union { unsigned u[4]; bf16x8 v; } F;
    F.u[0] = r0[0]; F.u[1] = r1[0]; F.u[2] = r0[1]; F.u[3] = r1[1];
    h[2 * mt + e] = F.v;
  }
}

#define MFMA32(A, B, C) __builtin_amdgcn_mfma_f32_32x32x16_bf16((A), (B), (C), 0, 0, 0)

__global__ __launch_bounds__(256, 1) void dyn_conv(
    const float* __restrict__ x, const unsigned short* __restrict__ w_ws,
    const float* __restrict__ b_ws, float* __restrict__ out) {
  // LDS frag order = w_ws layout: in[0..16) mida[16..48) midb[48..80)
  //                               out[80..96) short[96..104)
  __shared__ short wl[104 * 512];  // 106496 B
  __shared__ float bl[512];        //   2048 B

  const int s = blockIdx.x >> 4;
  const int chunk = blockIdx.x & 15;
  const int tid = threadIdx.x;
  const int wv = tid >> 6;       // 0..3
  const int l = tid & 63;
  const int l31 = l & 31;
  const int lh = l >> 5;

  const unsigned short* wbase = w_ws + (size_t)s * WS_WSHORTS;
  const float* xbase = x + (size_t)(s * 64) * 16384;

  float xr[4][8];  // 32 floats: this iter's 32 px x 64 ch slice for this lane
  auto load_xr = [&](int it2) {
    const int px0 = chunk * 1024 + it2 * 128 + wv * 32;
#pragma unroll
    for (int ks = 0; ks < 4; ++ks) {
      const float* xp =
          xbase + (size_t)(ks * 16 + lh * 8) * 16384 + px0 + l31;
#pragma unroll
      for (int j = 0; j < 8; ++j) xr[ks][j] = xp[(size_t)j * 16384];
    }
  };
  // iter-0 x loads first: HBM latency overlaps the weight staging below
  load_xr(0);

  // stage ALL weights -> LDS (w_ws frag layout is contiguous; copy verbatim)
  for (int f = wv; f < 104; f += 4)
    *(int4*)&wl[f * 512 + l * 8] = *(const int4*)&wbase[(size_t)f * 512 + l * 8];
  bl[tid] = b_ws[s * 512 + tid];
  bl[tid + 256] = b_ws[s * 512 + tid + 256];

  __syncthreads();

#pragma unroll 1
  for (int it = 0; it < 8; ++it) {
    const int px0 = chunk * 1024 + it * 128 + wv * 32;

    // pack current x regs -> bf16 B-frags (used by IN and SHORT stages)
    bf16x8 xf[4];
#pragma unroll
    for (int ks = 0; ks < 4; ++ks) {
      union { unsigned u[4]; bf16x8 v8; } uu;
#pragma unroll
      for (int j = 0; j < 4; ++j)
        uu.u[j] = pk2(xr[ks][2 * j], xr[ks][2 * j + 1]);
      xf[ks] = uu.v8;
    }
    // prefetch next iteration's x; latency overlaps all four MFMA stages
    if (it < 7) load_xr(it + 1);

    bf16x8 hA[8], hB2[8];

    // ---- stage IN: h1 = relu(k_in @ x + b_in)   (M=128, K=64) -> hA
#pragma unroll
    for (int mt = 0; mt < 4; ++mt) {
      f32x16 a0 = bias_init(bl + 0, mt, lh);
#pragma unroll
      for (int ks = 0; ks < 4; ++ks) {
        const bf16x8 A = *(const bf16x8*)&wl[(mt * 4 + ks) * 512 + l * 8];
        a0 = MFMA32(A, xf[ks], a0);
      }
      acc_to_bfrags1(a0, hA, mt);
    }

    // ---- stage MIDA: h2 = relu(k_mida @ h1 + b) (M=128, K=128) hA -> hB2
#pragma unroll
    for (int mt = 0; mt < 4; ++mt) {
      f32x16 a0 = bias_init(bl + 128, mt, lh);
#pragma unroll
      for (int ks = 0; ks < 8; ++ks) {
        const bf16x8 A = *(const bf16x8*)&wl[(16 + mt * 8 + ks) * 512 + l * 8];
        a0 = MFMA32(A, hA[ks], a0);
      }
      acc_to_bfrags1(a0, hB2, mt);
    }

    // ---- stage MIDB: h3 = relu(k_midb @ h2 + b) (M=128, K=128) hB2 -> hA
#pragma unroll
    for (int mt = 0; mt < 4; ++mt) {
      f32x16 a0 = bias_init(bl + 256, mt, lh);
#pragma unroll
      for (int ks = 0; ks < 8; ++ks) {
        const bf16x8 A = *(const bf16x8*)&wl[(48 + mt * 8 + ks) * 512 + l * 8];
        a0 = MFMA32(A, hB2[ks], a0);
      }
      acc_to_bfrags1(a0, hA, mt);
    }

    // ---- stage OUT: out = k_out@h3 + k_short@x + b_out + b_short  (M=64)
#pragma unroll
    for (int mt = 0; mt < 2; ++mt) {
      f32x16 a0 = bias_init(bl + 384, mt, lh);
      {
        const f32x16 bs = bias_init(bl + 448, mt, lh);
#pragma unroll
        for (int e = 0; e < 16; ++e) a0[e] += bs[e];
      }
#pragma unroll
      for (int ks = 0; ks < 4; ++ks) {  // shortcut: K=64, B = x frags
        const bf16x8 A = *(const bf16x8*)&wl[(96 + mt * 4 + ks) * 512 + l * 8];
        a0 = MFMA32(A, xf[ks], a0);
      }
#pragma unroll
      for (int ks = 0; ks < 8; ++ks) {  // k_out: K=128, B = h3
        const bf16x8 A = *(const bf16x8*)&wl[(80 + mt * 8 + ks) * 512 + l * 8];
        a0 = MFMA32(A, hA[ks], a0);
      }
#pragma unroll
      for (int g = 0; g < 4; ++g) {
#pragma unroll
        for (int q = 0; q < 4; ++q) {
          const int row = mt * 32 + 8 * g + 4 * lh + q;
          out[(size_t)(s * 64 + row) * 16384 + px0 + l31] = a0[4 * g + q];
        }
      }
    }
  }
}

// ---------------------------------------------------------------------------
extern "C" void kernel_launch(void* const* d_in, const int* in_sizes, int n_in,
                              void* d_out, int out_size, void* d_ws,
                              size_t ws_size, hipStream_t stream) {
  (void)in_sizes; (void)n_in; (void)out_size; (void)ws_size;
  const float* x   = (const float*)d_in[0];
  const float* lat = (const float*)d_in[1];
  const float* W   = (const float*)d_in[2];
  const float* b   = (const float*)d_in[3];
  unsigned short* w_ws = (unsigned short*)d_ws;
  float* b_ws = (float*)((char*)d_ws + WS_BOFF);
  unsigned short* ah_ws = (unsigned short*)((char*)d_ws + WS_AHOFF);
  unsigned short* al_ws = (unsigned short*)((char*)d_ws + WS_ALOFF);
  float* out = (float*)d_out;

  lat_prep<<<dim3(4), dim3(256), 0, stream>>>(lat, ah_ws, al_ws);
  hyper_gemm<<<dim3(840), dim3(256), 0, stream>>>(W, b, ah_ws, al_ws, w_ws, b_ws);
  dyn_conv<<<dim3(256), dim3(256), 0, stream>>>(x, w_ws, b_ws, out);
}

// Round 5
// 272.918 us; speedup vs baseline: 2.0586x; 1.5687x over previous
//
#include <hip/hip_runtime.h>
#include <cstdint>
#include <cstddef>

// ---------------------------------------------------------------------------
// DynaResidualBlock: hypernet GEMM (MFMA, hi/lo bf16 split = fp32-accurate)
//  -> per-sample 1x1 conv chain (bf16 MFMA)
//   FIN=64 FOUT=64 FH=128 LAT=512  B=16  H*W=16384
//   sizes = [8192,16384,16384,8192,4096,128,128,128,64,64], KTOT=53760
// ---------------------------------------------------------------------------

typedef short bf16x8 __attribute__((ext_vector_type(8)));   // 8 bf16 = 4 VGPRs
typedef float f32x4  __attribute__((ext_vector_type(4)));
typedef float f32x16 __attribute__((ext_vector_type(16)));  // MFMA 32x32 acc

#define DEVFN static __device__ __forceinline__

constexpr int WELEM      = 53248;           // bf16 weight elements per sample
constexpr size_t WS_WSHORTS = (size_t)WELEM;
constexpr size_t WS_WBYTES_TOT = (size_t)16 * WELEM * 2;     // 1,703,936
constexpr size_t WS_BOFF  = WS_WBYTES_TOT;                   // b_ws: 16*512 f32
constexpr size_t WS_AHOFF = WS_BOFF + 16 * 512 * 4;          // ah frags: 16 KB
constexpr size_t WS_ALOFF = WS_AHOFF + 16384;                // al frags: 16 KB

DEVFN unsigned bf16rne(float f) {
  unsigned u = __builtin_bit_cast(unsigned, f);
  return (u + 0x7fffu + ((u >> 16) & 1u)) >> 16;
}
DEVFN unsigned pk2(float lo, float hi) {
  return bf16rne(lo) | (bf16rne(hi) << 16);
}

// ---------------------------------------------------------------------------
// Kernel 0: lat -> hi/lo bf16 A-frags for mfma_16x16x32.
// frag element (s, lane l, j): A[m=l&15][k = s*32 + (l>>4)*8 + j]
// stored at ah_ws[(s*64+l)*8 + j]. 1024 (s,l) pairs.
// ---------------------------------------------------------------------------
__global__ __launch_bounds__(256) void lat_prep(
    const float* __restrict__ lat, unsigned short* __restrict__ ah_ws,
    unsigned short* __restrict__ al_ws) {
  const int id = blockIdx.x * 256 + threadIdx.x;  // 0..1023
  const int s = id >> 6, l = id & 63;
  const int m = l & 15, q = l >> 4;
  const float* ap = lat + m * 512 + s * 32 + q * 8;
  float f[8];
#pragma unroll
  for (int j = 0; j < 8; ++j) f[j] = ap[j];
  unsigned H[4], L[4];
#pragma unroll
  for (int p = 0; p < 4; ++p) {
    const unsigned u0 = __builtin_bit_cast(unsigned, f[2 * p]);
    const unsigned u1 = __builtin_bit_cast(unsigned, f[2 * p + 1]);
    const unsigned h0 = u0 & 0xFFFF0000u, h1 = u1 & 0xFFFF0000u;
    H[p] = (h0 >> 16) | h1;
    const float lo0 = f[2 * p] - __builtin_bit_cast(float, h0);
    const float lo1 = f[2 * p + 1] - __builtin_bit_cast(float, h1);
    L[p] = pk2(lo0, lo1);
  }
  *(uint4*)&ah_ws[(size_t)(s * 64 + l) * 8] = make_uint4(H[0], H[1], H[2], H[3]);
  *(uint4*)&al_ws[(size_t)(s * 64 + l) * 8] = make_uint4(L[0], L[1], L[2], L[3]);
}

// ---------------------------------------------------------------------------
// Kernel 1: ks = lat @ W.T + bias via MFMA 16x16x32 (hi/lo split, 3 mfma/step)
// One 16-column tile per wave; 3360 tiles = 840 blocks x 4 waves.
// Wave streams its 16 W rows (columns of ks) with an 8-step float4 ring
// (16 KB in flight per wave). Epilogue scatters to frag-layout bf16 ws.
// ---------------------------------------------------------------------------
#define MFMA16(A, B, C) __builtin_amdgcn_mfma_f32_16x16x32_bf16((A), (B), (C), 0, 0, 0)

__global__ __launch_bounds__(256, 2) void hyper_gemm(
    const float* __restrict__ W, const float* __restrict__ bias,
    const unsigned short* __restrict__ ah_ws,
    const unsigned short* __restrict__ al_ws,
    unsigned short* __restrict__ w_ws, float* __restrict__ b_ws) {
  const int tid = threadIdx.x;
  const int wv = tid >> 6;
  const int l = tid & 63;
  const int q = l >> 4;
  const int g = blockIdx.x * 4 + wv;  // tile id 0..3359
  const int n0 = g * 16;
  const int n = n0 + (l & 15);

  // A frags (shared by all waves; L2-hot)
  bf16x8 Ah[16], Al[16];
#pragma unroll
  for (int s = 0; s < 16; ++s) {
    Ah[s] = *(const bf16x8*)&ah_ws[(size_t)(s * 64 + l) * 8];
    Al[s] = *(const bf16x8*)&al_ws[(size_t)(s * 64 + l) * 8];
  }

  // B stream: lane reads W[n][s*32 + q*8 .. +8]
  const float* bp = W + (size_t)n * 512 + q * 8;
  float4 ld[8][2];
#pragma unroll
  for (int s = 0; s < 8; ++s) {
    ld[s][0] = *(const float4*)(bp + s * 32);
    ld[s][1] = *(const float4*)(bp + s * 32 + 4);
  }

  f32x4 acc = {0.f, 0.f, 0.f, 0.f};
#pragma unroll
  for (int s = 0; s < 16; ++s) {
    const float4 b0 = ld[s & 7][0];
    const float4 b1 = ld[s & 7][1];
    if (s < 8) {
      ld[s][0] = *(const float4*)(bp + (s + 8) * 32);
      ld[s][1] = *(const float4*)(bp + (s + 8) * 32 + 4);
    }
    const float f[8] = {b0.x, b0.y, b0.z, b0.w, b1.x, b1.y, b1.z, b1.w};
    union { unsigned u[4]; bf16x8 v; } BH, BL;
#pragma unroll
    for (int p = 0; p < 4; ++p) {
      const unsigned u0 = __builtin_bit_cast(unsigned, f[2 * p]);
      const unsigned u1 = __builtin_bit_cast(unsigned, f[2 * p + 1]);
      const unsigned h0 = u0 & 0xFFFF0000u, h1 = u1 & 0xFFFF0000u;
      BH.u[p] = (h0 >> 16) | h1;
      const float lo0 = f[2 * p] - __builtin_bit_cast(float, h0);
      const float lo1 = f[2 * p + 1] - __builtin_bit_cast(float, h1);
      BL.u[p] = pk2(lo0, lo1);
    }
    acc = MFMA16(Ah[s], BH.v, acc);
    acc = MFMA16(Ah[s], BL.v, acc);
    acc = MFMA16(Al[s], BH.v, acc);
  }

  // epilogue: lane holds column n, samples b = q*4 + r  (D: col=l&15, row=q*4+r)
  const float bv = bias[n];
  if (n0 >= 53248) {  // conv biases: fp32, per-sample contiguous [512]
    const int j = n - 53248;
#pragma unroll
    for (int r = 0; r < 4; ++r) b_ws[(q * 4 + r) * 512 + j] = acc[r] + bv;
    return;
  }
  int fragbase, off, kbits;
  float scale;
  if (n < 8192)       { fragbase = 0;  off = 0;     kbits = 6; scale = 0.08838834764831845f; }
  else if (n < 24576) { fragbase = 16; off = 8192;  kbits = 7; scale = 0.08838834764831845f; }
  else if (n < 40960) { fragbase = 48; off = 24576; kbits = 7; scale = 0.08838834764831845f; }
  else if (n < 49152) { fragbase = 80; off = 40960; kbits = 7; scale = 0.125f; }
  else                { fragbase = 96; off = 49152; kbits = 6; scale = 0.125f; }
  const int r0 = n - off;
  const int m = r0 >> kbits;
  const int k = r0 & ((1 << kbits) - 1);
  const int mt = m >> 5, ks = k >> 4;
  const int lane = (m & 31) + 32 * ((k >> 3) & 1);
  const int j = k & 7;
  const int frag = fragbase + mt * (1 << (kbits - 4)) + ks;
  const size_t eoff = (size_t)frag * 512 + lane * 8 + j;  // in shorts
#pragma unroll
  for (int r = 0; r < 4; ++r) {
    const float v = (acc[r] + bv) * scale;
    w_ws[(size_t)(q * 4 + r) * WS_WSHORTS + eoff] = (unsigned short)bf16rne(v);
  }
}

// ---------------------------------------------------------------------------
// Kernel 2: per-sample conv chain, v6 = v1 structure + LDS diet for 2 blk/CU.
// LESSONS (counter-verified):
//   v1: 256thr nt=2, h in LDS, Am in regs -> 236 VGPR no spill, 76 us, but
//       141 KB LDS -> 1 blk/CU -> 1 wave/SIMD -> latency-bound (MfmaUtil 14%).
//   v2/v4: 512-thr blocks -> compiler caps at 128 VGPR -> ~1 GB spill.
//   v3/v5: "h in registers" at 256 thr -> VALU-addressable live set > 256
//       arch VGPRs (v0-v255) -> spill (FETCH/WRITE counters 3-9x ideal).
// => keep v1's per-wave-LDS h handoff (proven 236 reg / no spill), shrink
//    LDS below 80 KB so TWO blocks fit per CU (2 waves/SIMD, 2x latency
//    hiding): nt=1 (h buf 8 KB/wave), stage only midb+short in LDS (40
//    frags), read IN/k_out A-frags straight from w_ws (L2/L1-resident,
//    104 KB/sample; all waves read identical addresses).
// LDS = 40960 (wl) + 32768 (hl) + 2048 (bl) = 75776 B.  Grid 512 blocks
// (sample = blk>>5, chunk = blk&31), 4 waves, 32 px/wave/iter, 4 iters.
// h frag mapping (v1-verified, nt dropped):
//   C elem a0[4g+t] (ch = mt*32+8g+4lh+t, px l31) -> frag kstep=2mt+(g>>1),
//   short idx (l31+32*(g&1))*8 + lh*4 + t; reader lane l' reads shorts
//   l'*8+j' as B elem (n=l'&31, k5=8*(l'>>5)+j') => k5 = 8sub+4lh+t. OK.
// ---------------------------------------------------------------------------

DEVFN f32x16 bias_init(const float* bl, int mt, int lh) {
  f32x16 a;
#pragma unroll
  for (int g = 0; g < 4; ++g) {
    const float4 bv = *(const float4*)&bl[mt * 32 + 8 * g + 4 * lh];
    a[4 * g + 0] = bv.x; a[4 * g + 1] = bv.y;
    a[4 * g + 2] = bv.z; a[4 * g + 3] = bv.w;
  }
  return a;
}

// write relu(acc) as bf16 into wave-private h buffer (8 frags, B-frag layout)
DEVFN void write_h1(short* hb, int mt, int l31, int lh, const f32x16& a0) {
#pragma unroll
  for (int g = 0; g < 4; ++g) {
    const int kstep = mt * 2 + (g >> 1);
    const int sub = g & 1;
    const int base = kstep * 512 + (l31 + 32 * sub) * 8 + lh * 4;
    uint2 w0;
    w0.x = pk2(fmaxf(a0[4 * g + 0], 0.f), fmaxf(a0[4 * g + 1], 0.f));
    w0.y = pk2(fmaxf(a0[4 * g + 2], 0.f), fmaxf(a0[4 * g + 3], 0.f));
    *(uint2*)&hb[base] = w0;
  }
}

#define MFMA32(A, B, C) __builtin_amdgcn_mfma_f32_32x32x16_bf16((A), (B), (C), 0, 0, 0)

__global__ __launch_bounds__(256, 1) void dyn_conv(
    const float* __restrict__ x, const unsigned short* __restrict__ w_ws,
    const float* __restrict__ b_ws, float* __restrict__ out) {
  // wl: midb frags 0..31 (w_ws 48..79), short frags 32..39 (w_ws 96..103)
  __shared__ short wl[40 * 512];   // 40960 B
  __shared__ short hl[4][4096];    // 32768 B  per-wave 8 h-frags
  __shared__ float bl[512];        //  2048 B

  const int s = blockIdx.x >> 5;
  const int chunk = blockIdx.x & 31;
  const int tid = threadIdx.x;
  const int wv = tid >> 6;       // 0..3
  const int l = tid & 63;
  const int l31 = l & 31;
  const int lh = l >> 5;

  const unsigned short* wbase = w_ws + (size_t)s * WS_WSHORTS;
  const float* xbase = x + (size_t)(s * 64) * 16384;

  float xr[4][8];  // 32 floats: this iter's 32 px x 64 ch slice for this lane
  auto load_xr = [&](int it2) {
    const int px0 = chunk * 512 + it2 * 128 + wv * 32;
#pragma unroll
    for (int ks = 0; ks < 4; ++ks) {
      const float* xp =
          xbase + (size_t)(ks * 16 + lh * 8) * 16384 + px0 + l31;
#pragma unroll
      for (int j = 0; j < 8; ++j) xr[ks][j] = xp[(size_t)j * 16384];
    }
  };
  // iter-0 x loads first: HBM latency overlaps the staging below
  load_xr(0);

  // k_mida A-frags -> registers (32 frags; MFMA-only use -> AGPR-eligible)
  bf16x8 Am[32];
#pragma unroll
  for (int i = 0; i < 32; ++i)
    Am[i] = *(const bf16x8*)&wbase[(size_t)(16 + i) * 512 + l * 8];

  // stage midb + short weights -> LDS (frag layout preserved)
  for (int f = wv; f < 40; f += 4) {
    const int fg = (f < 32) ? 48 + f : 96 + (f - 32);
    *(int4*)&wl[f * 512 + l * 8] = *(const int4*)&wbase[(size_t)fg * 512 + l * 8];
  }
  bl[tid] = b_ws[s * 512 + tid];
  bl[tid + 256] = b_ws[s * 512 + tid + 256];

  __syncthreads();

  short* hb = &hl[wv][0];

#pragma unroll 1
  for (int it = 0; it < 4; ++it) {
    const int px0 = chunk * 512 + it * 128 + wv * 32;

    // pack current x regs -> bf16 B-frags (used by IN and SHORT stages)
    bf16x8 xf[4];
#pragma unroll
    for (int ks = 0; ks < 4; ++ks) {
      union { unsigned u[4]; bf16x8 v8; } uu;
#pragma unroll
      for (int j = 0; j < 4; ++j)
        uu.u[j] = pk2(xr[ks][2 * j], xr[ks][2 * j + 1]);
      xf[ks] = uu.v8;
    }
    // prefetch next iteration's x; latency overlaps all four MFMA stages
    if (it < 3) load_xr(it + 1);

    // ---- stage IN: h1 = relu(k_in @ x + b_in)  (M=128, K=64)
    // A-frags from global (w_ws frags 0..15; L1/L2-hot, same addr all waves)
#pragma unroll
    for (int mt = 0; mt < 4; ++mt) {
      f32x16 a0 = bias_init(bl + 0, mt, lh);
#pragma unroll
      for (int ks = 0; ks < 4; ++ks) {
        const bf16x8 A = *(const bf16x8*)&wbase[(size_t)(mt * 4 + ks) * 512 + l * 8];
        a0 = MFMA32(A, xf[ks], a0);
      }
      write_h1(hb, mt, l31, lh, a0);
    }

    bf16x8 hB[8];

    // ---- stage MIDA (A from Am registers)      (M=128, K=128)
#pragma unroll
    for (int i = 0; i < 8; ++i) hB[i] = *(const bf16x8*)&hb[i * 512 + l * 8];
#pragma unroll
    for (int mt = 0; mt < 4; ++mt) {
      f32x16 a0 = bias_init(bl + 128, mt, lh);
#pragma unroll
      for (int ks = 0; ks < 8; ++ks) a0 = MFMA32(Am[mt * 8 + ks], hB[ks], a0);
      write_h1(hb, mt, l31, lh, a0);
    }

    // ---- stage MIDB (A from LDS wl 0..31)      (M=128, K=128)
#pragma unroll
    for (int i = 0; i < 8; ++i) hB[i] = *(const bf16x8*)&hb[i * 512 + l * 8];
#pragma unroll
    for (int mt = 0; mt < 4; ++mt) {
      f32x16 a0 = bias_init(bl + 256, mt, lh);
#pragma unroll
      for (int ks = 0; ks < 8; ++ks) {
        const bf16x8 A = *(const bf16x8*)&wl[(mt * 8 + ks) * 512 + l * 8];
        a0 = MFMA32(A, hB[ks], a0);
      }
      write_h1(hb, mt, l31, lh, a0);
    }

    // ---- stage OUT: out = k_out@h3 + k_short@x + b_out + b_short  (M=64)
#pragma unroll
    for (int i = 0; i < 8; ++i) hB[i] = *(const bf16x8*)&hb[i * 512 + l * 8];
#pragma unroll
    for (int mt = 0; mt < 2; ++mt) {
      f32x16 a0 = bias_init(bl + 384, mt, lh);
      {
        const f32x16 bs = bias_init(bl + 448, mt, lh);
#pragma unroll
        for (int e = 0; e < 16; ++e) a0[e] += bs[e];
      }
#pragma unroll
      for (int ks = 0; ks < 4; ++ks) {  // shortcut: K=64, A from LDS wl 32..39
        const bf16x8 A = *(const bf16x8*)&wl[(32 + mt * 4 + ks) * 512 + l * 8];
        a0 = MFMA32(A, xf[ks], a0);
      }
#pragma unroll
      for (int ks = 0; ks < 8; ++ks) {  // k_out: K=128, A from global 80..95
        const bf16x8 A =
            *(const bf16x8*)&wbase[(size_t)(80 + mt * 8 + ks) * 512 + l * 8];
        a0 = MFMA32(A, hB[ks], a0);
      }
#pragma unroll
      for (int g = 0; g < 4; ++g) {
#pragma unroll
        for (int q = 0; q < 4; ++q) {
          const int row = mt * 32 + 8 * g + 4 * lh + q;
          out[(size_t)(s * 64 + row) * 16384 + px0 + l31] = a0[4 * g + q];
        }
      }
    }
  }
}

// ---------------------------------------------------------------------------
extern "C" void kernel_launch(void* const* d_in, const int* in_sizes, int n_in,
                              void* d_out, int out_size, void* d_ws,
                              size_t ws_size, hipStream_t stream) {
  (void)in_sizes; (void)n_in; (void)out_size; (void)ws_size;
  const float* x   = (const float*)d_in[0];
  const float* lat = (const float*)d_in[1];
  const float* W   = (const float*)d_in[2];
  const float* b   = (const float*)d_in[3];
  unsigned short* w_ws = (unsigned short*)d_ws;
  float* b_ws = (float*)((char*)d_ws + WS_BOFF);
  unsigned short* ah_ws = (unsigned short*)((char*)d_ws + WS_AHOFF);
  unsigned short* al_ws = (unsigned short*)((char*)d_ws + WS_ALOFF);
  float* out = (float*)d_out;

  lat_prep<<<dim3(4), dim3(256), 0, stream>>>(lat, ah_ws, al_ws);
  hyper_gemm<<<dim3(840), dim3(256), 0, stream>>>(W, b, ah_ws, al_ws, w_ws, b_ws);
  dyn_conv<<<dim3(512), dim3(256), 0, stream>>>(x, w_ws, b_ws, out);
}